// Round 6
// baseline (27370.746 us; speedup 1.0000x reference)
//
#include <hip/hip_runtime.h>
#include <hip/hip_bf16.h>
#include <hip/hip_fp16.h>
#include <stdint.h>

#define B_ 128
#define S_ 512
#define E_ 256
#define H2_ 512
#define G_ 1024      // 4*E
#define DG_ 2048     // 4*H2
#define M_ (B_*S_)   // 65536

typedef float f32x4 __attribute__((ext_vector_type(4)));
typedef short s16x8 __attribute__((ext_vector_type(8)));
typedef _Float16 h16x2 __attribute__((ext_vector_type(2)));

__device__ __forceinline__ float sigm(float x){ return 1.f/(1.f+__expf(-x)); }
__device__ __forceinline__ float tanh_f(float x){ return 1.f - 2.f/(__expf(2.f*x)+1.f); }

// ---------------- fp8 e4m3fn encode/decode ----------------
__device__ __forceinline__ uint32_t enc_e4m3(float f){
  uint32_t u = __float_as_uint(f);
  uint32_t s = (u >> 24) & 0x80u;
  float af = fabsf(f);
  if (!(af > 0.f)) return s;
  if (af >= 448.f) return s | 0x7Eu;
  int ex = (int)((u >> 23) & 0xFF) - 127;
  uint32_t man = u & 0x7FFFFFu;
  int bexp = ex + 7;
  if (bexp <= 0){
    uint32_t qi = (uint32_t)rintf(af * 512.f);
    if (qi > 8u) qi = 8u;
    return s | qi;
  }
  uint32_t keep = man >> 20;
  uint32_t rest = man & 0xFFFFFu;
  const uint32_t half = 0x80000u;
  if (rest > half || (rest == half && (keep & 1u))) keep++;
  if (keep == 8u){ keep = 0u; bexp++; }
  if (bexp >= 16) return s | 0x7Eu;
  if (bexp == 15 && keep == 7u) keep = 6u; // avoid NaN encoding
  return s | ((uint32_t)bexp << 3) | keep;
}

__device__ __forceinline__ float dec_e4m3(uint32_t byte){
  uint32_t s = (byte & 0x80u) << 24;
  uint32_t e = (byte >> 3) & 0xFu;
  uint32_t m = byte & 7u;
  float v;
  if (e == 0) v = (float)m * 0.001953125f;
  else v = __uint_as_float(((e + 120u) << 23) | (m << 20));
  return __uint_as_float(__float_as_uint(v) | s);
}

__device__ __forceinline__ void fp8x4_to_f32x4(uint32_t w, float* o){
#if __has_builtin(__builtin_amdgcn_cvt_pk_f32_fp8)
  auto lo = __builtin_amdgcn_cvt_pk_f32_fp8((int)w, false);
  auto hi = __builtin_amdgcn_cvt_pk_f32_fp8((int)w, true);
  o[0]=lo[0]; o[1]=lo[1]; o[2]=hi[0]; o[3]=hi[1];
#else
  o[0]=dec_e4m3(w & 0xFFu); o[1]=dec_e4m3((w>>8)&0xFFu);
  o[2]=dec_e4m3((w>>16)&0xFFu); o[3]=dec_e4m3(w>>24);
#endif
}

__device__ __forceinline__ float dot2_f16(uint32_t a, uint32_t b, float acc){
#if __has_builtin(__builtin_amdgcn_fdot2)
  return __builtin_amdgcn_fdot2(__builtin_bit_cast(h16x2,a), __builtin_bit_cast(h16x2,b), acc, false);
#else
  __half2 ah = __builtin_bit_cast(__half2, a), bh = __builtin_bit_cast(__half2, b);
  float2 af = __half22float2(ah), bf = __half22float2(bh);
  return fmaf(af.x, bf.x, fmaf(af.y, bf.y, acc));
#endif
}

// ---------------- weight prep ----------------
__global__ __launch_bounds__(512) void k_prep_enc(
    const float* __restrict__ wf, const float* __restrict__ wb,
    const float* __restrict__ bihf, const float* __restrict__ bhhf,
    const float* __restrict__ bihb, const float* __restrict__ bhhb,
    ushort* __restrict__ Wenc, float* __restrict__ bsum){
  int n = blockIdx.x, d = threadIdx.x;
  const float* src = (n < G_) ? (wf + (size_t)n*H2_) : (wb + (size_t)(n-G_)*H2_);
  __hip_bfloat16 h = __float2bfloat16(src[d]);
  Wenc[(size_t)n*H2_ + d] = __builtin_bit_cast(ushort, h);
  if (d == 0) bsum[n] = (n < G_) ? (bihf[n] + bhhf[n]) : (bihb[n-G_] + bhhb[n-G_]);
}

__global__ __launch_bounds__(256) void k_prep_whh(
    const float* __restrict__ whf, const float* __restrict__ whb, uint8_t* __restrict__ whh8){
  int r = blockIdx.x; int d = threadIdx.x;
  int dir = r >> 10, g = r & 1023;
  float v = dir ? whb[(size_t)g*E_ + d] : whf[(size_t)g*E_ + d];
  whh8[((size_t)dir*G_ + g)*E_ + d] = (uint8_t)enc_e4m3(v);
}

__global__ __launch_bounds__(64) void k_prep_dec(
    const float* __restrict__ wd, const float* __restrict__ bih, const float* __restrict__ bhh,
    uint4* __restrict__ wdt, float* __restrict__ bsumd){
  int row = blockIdx.x, u = threadIdx.x; // u in [0,64)
  const float* src = wd + (size_t)row*H2_ + u*8;
  union { _Float16 h[8]; uint4 q; } pk;
  #pragma unroll
  for (int i=0;i<8;i++) pk.h[i] = (_Float16)src[i];
  wdt[(size_t)u*DG_ + row] = pk.q;
  if (u == 0) bsumd[row] = bih[row] + bhh[row];
}

// ---------------- input stats ----------------
__global__ __launch_bounds__(512) void k_xstat(
    const float* __restrict__ X, float* __restrict__ SX, float* __restrict__ SX2){
  int b = blockIdx.x, d = threadIdx.x;
  const float* xb = X + (size_t)b*S_*H2_;
  float s=0.f, s2=0.f;
  for (int t=0;t<S_;++t){ float v = xb[(size_t)t*H2_ + d]; s += v; s2 = fmaf(v,v,s2); }
  SX[(size_t)b*H2_+d]=s; SX2[(size_t)b*H2_+d]=s2;
}

// ---------------- pre-GEMM: pre[m][n] = X[m][:] . Wenc[n][:] + bsum[n] ----------------
__global__ __launch_bounds__(256) void k_gemm_pre(
    const float* __restrict__ X, const ushort* __restrict__ Wenc,
    const float* __restrict__ bsum, __hip_bfloat16* __restrict__ pre){
  __shared__ ushort As[128][64];
  __shared__ ushort Bs[128][64];
  int n0 = blockIdx.x * 128, m0 = blockIdx.y * 128;
  int tid = threadIdx.x, lane = tid & 63, wid = tid >> 6;
  int wr = wid >> 1, wc = wid & 1;
  f32x4 acc[4][4] = {};
  for (int kt=0; kt<8; ++kt){
    int k0 = kt*64;
    #pragma unroll
    for (int it=0; it<4; ++it){
      int slot = tid + it*256;
      int r = slot >> 3, c8 = (slot & 7)*8;
      const float* ap = X + (size_t)(m0+r)*512 + k0 + c8;
      float4 a0 = *(const float4*)ap;
      float4 a1 = *(const float4*)(ap+4);
      union { __hip_bfloat16 h[8]; uint4 q; } pk;
      pk.h[0]=__float2bfloat16(a0.x); pk.h[1]=__float2bfloat16(a0.y);
      pk.h[2]=__float2bfloat16(a0.z); pk.h[3]=__float2bfloat16(a0.w);
      pk.h[4]=__float2bfloat16(a1.x); pk.h[5]=__float2bfloat16(a1.y);
      pk.h[6]=__float2bfloat16(a1.z); pk.h[7]=__float2bfloat16(a1.w);
      *(uint4*)&As[r][c8] = pk.q;
      *(uint4*)&Bs[r][c8] = *(const uint4*)(Wenc + (size_t)(n0+r)*512 + k0 + c8);
    }
    __syncthreads();
    #pragma unroll
    for (int kk=0; kk<2; ++kk){
      int krow = kk*32 + (lane>>4)*8;
      s16x8 af[4], bf[4];
      #pragma unroll
      for (int mi=0;mi<4;mi++) af[mi] = *(const s16x8*)&As[wr*64+mi*16+(lane&15)][krow];
      #pragma unroll
      for (int ni=0;ni<4;ni++) bf[ni] = *(const s16x8*)&Bs[wc*64+ni*16+(lane&15)][krow];
      #pragma unroll
      for (int mi=0;mi<4;mi++){
        #pragma unroll
        for (int ni=0;ni<4;ni++)
          acc[mi][ni] = __builtin_amdgcn_mfma_f32_16x16x32_bf16(af[mi], bf[ni], acc[mi][ni], 0,0,0);
      }
    }
    __syncthreads();
  }
  #pragma unroll
  for (int ni=0; ni<4; ++ni){
    int n = n0 + wc*64 + ni*16 + (lane&15);
    float bs = bsum[n];
    #pragma unroll
    for (int mi=0; mi<4; ++mi){
      int mb = m0 + wr*64 + mi*16 + (lane>>4)*4;
      #pragma unroll
      for (int r2=0;r2<4;r2++)
        pre[(size_t)(mb+r2)*DG_ + n] = __float2bfloat16(acc[mi][ni][r2] + bs);
    }
  }
}

// ---------------- encoder recurrence v6 ----------------
// 256 wgs = (dir, b), 512 threads. Thread j owns FULL k=256 of two gate rows:
//   rowA = j       (j<256: gate i of unit j;   j>=256: gate f of unit j-256)
//   rowB = j + 512 (j<256: gate g of unit j;   j>=256: gate o of unit j-256)
// rowB weights (g,o = 128 KB fp8) live in LDS, chunk-major wlds[u*512+j] so a
// wave's ds_read_b128 is lane-consecutive (verified conflict-free pattern).
// rowA weights (i,f) are STREAMED from global each step: 16 uint4/thread, same
// addresses every step -> L1/L2-resident (512 KB total footprint). No
// loop-carried weight registers -> nothing for the allocator to spill.
// Gate exchange via abuf: thread j<256 computes sig(i)*tanh(g); partner j+256
// holds (c, f, o) and the h-state. 2 barriers/step, double-buffered hbuf.
__global__ __launch_bounds__(512) void k_enc_rec(
    const __hip_bfloat16* __restrict__ pre, const uint8_t* __restrict__ whh8,
    float* __restrict__ SH, float* __restrict__ x0){
  int wg = blockIdx.x;
  int dir = wg >> 7, b = wg & 127;
  int j = threadIdx.x;
  __shared__ float hbuf[2][256];
  __shared__ float abuf[256];
  __shared__ uint4 wlds[16*512];   // 128 KB

  // stage g,o rows into LDS: thread j stages gate row 512+j
  {
    const uint4* src = (const uint4*)(whh8 + ((size_t)dir*G_ + 512 + j)*E_);
    #pragma unroll
    for (int u=0; u<16; ++u) wlds[u*512 + j] = src[u];
  }
  if (j < 256) hbuf[0][j] = 0.f;
  float c = 0.f, sh = 0.f;
  const __hip_bfloat16* preB = pre + ((size_t)b*S_)*DG_ + dir*G_;
  const uint4* ga = (const uint4*)(whh8 + ((size_t)dir*G_ + j)*E_);  // rowA (global)
  const uint4* wl = wlds + j;                                        // rowB (LDS)
  int t0 = dir ? (S_-1) : 0;
  float p0 = __bfloat162float(preB[(size_t)t0*DG_ + j]);
  float p1 = __bfloat162float(preB[(size_t)t0*DG_ + j + 512]);
  __syncthreads();

#define WORD4(WA, WB, HI) do { \
    float4 hv = h4[HI]; \
    float da[4], db[4]; \
    fp8x4_to_f32x4(WA, da); fp8x4_to_f32x4(WB, db); \
    a0 = fmaf(da[0],hv.x,a0); a0 = fmaf(da[1],hv.y,a0); \
    a0 = fmaf(da[2],hv.z,a0); a0 = fmaf(da[3],hv.w,a0); \
    a1 = fmaf(db[0],hv.x,a1); a1 = fmaf(db[1],hv.y,a1); \
    a1 = fmaf(db[2],hv.z,a1); a1 = fmaf(db[3],hv.w,a1); \
  } while(0)
#define CHUNK(UU) do { \
    uint4 wa = ga[UU]; \
    uint4 wb = wl[(UU)*512]; \
    WORD4(wa.x, wb.x, (UU)*4+0); WORD4(wa.y, wb.y, (UU)*4+1); \
    WORD4(wa.z, wb.z, (UU)*4+2); WORD4(wa.w, wb.w, (UU)*4+3); \
  } while(0)

  int pb = 0;
  for (int s=0; s<S_; ++s){
    float a0 = p0, a1 = p1;                 // pre-activations folded in
    const float4* h4 = (const float4*)hbuf[pb];
    CHUNK(0);  CHUNK(1);  CHUNK(2);  CHUNK(3);
    CHUNK(4);  CHUNK(5);  CHUNK(6);  CHUNK(7);
    CHUNK(8);  CHUNK(9);  CHUNK(10); CHUNK(11);
    CHUNK(12); CHUNK(13); CHUNK(14); CHUNK(15);
    // prefetch next step's pre
    if (s+1 < S_){
      int tn = dir ? (S_-2-s) : (s+1);
      p0 = __bfloat162float(preB[(size_t)tn*DG_ + j]);
      p1 = __bfloat162float(preB[(size_t)tn*DG_ + j + 512]);
    }
    if (j < 256) abuf[j] = sigm(a0) * tanh_f(a1);   // sig(i)*tanh(g)
    __syncthreads();
    if (j >= 256){
      int jj = j - 256;
      c = sigm(a0)*c + abuf[jj];                     // sig(f)*c + sig(i)*tanh(g)
      float hn = sigm(a1)*tanh_f(c);                 // sig(o)*tanh(c)
      hbuf[pb^1][jj] = hn;
      sh += hn;
      if ((dir==0 && s==S_-1) || (dir==1 && s==0))
        x0[(size_t)b*H2_ + dir*E_ + jj] = hn;
    }
    __syncthreads();
    pb ^= 1;
  }
#undef CHUNK
#undef WORD4
  if (j >= 256) SH[((size_t)dir*B_ + b)*E_ + (j-256)] = sh;
}

// ---------------- decoder + ae_loss: 128 wgs = b, 512 thr = hidden dim ----------------
#define EPS_CONV 2e-6f
__global__ __launch_bounds__(512) void k_dec(
    const float* __restrict__ X, const uint4* __restrict__ wdt,
    const float* __restrict__ bsumd, const float* __restrict__ x0,
    const float* __restrict__ SX, const float* __restrict__ SX2,
    float* __restrict__ loss_b){
  int b = blockIdx.x, j = threadIdx.x;
  __shared__ _Float16 hl[512];
  __shared__ float red[512];
  float h = x0[(size_t)b*H2_ + j];
  hl[j] = (_Float16)h;
  float bi = bsumd[j], bg = bsumd[j+1024], bo = bsumd[j+1536];
  float sxp = 0.f, x2p = 0.f, lacc = 0.f;
  const float* xb = X + (size_t)b*S_*H2_;
  int done = S_;
  __syncthreads();
  for (int s=0; s<S_; ++s){
    float ai = bi, ag = bg, ao = bo;
    const uint4* hp = (const uint4*)hl;
    const uint4* wi = wdt + j;
    const uint4* wgp = wdt + j + 1024;
    const uint4* wo = wdt + j + 1536;
    #pragma unroll 8
    for (int u=0; u<64; ++u){
      uint4 hv = hp[u];
      uint4 a = wi[(size_t)u*DG_];
      uint4 g = wgp[(size_t)u*DG_];
      uint4 o = wo[(size_t)u*DG_];
      ai = dot2_f16(a.x, hv.x, ai); ai = dot2_f16(a.y, hv.y, ai);
      ai = dot2_f16(a.z, hv.z, ai); ai = dot2_f16(a.w, hv.w, ai);
      ag = dot2_f16(g.x, hv.x, ag); ag = dot2_f16(g.y, hv.y, ag);
      ag = dot2_f16(g.z, hv.z, ag); ag = dot2_f16(g.w, hv.w, ag);
      ao = dot2_f16(o.x, hv.x, ao); ao = dot2_f16(o.y, hv.y, ao);
      ao = dot2_f16(o.z, hv.z, ao); ao = dot2_f16(o.w, hv.w, ao);
    }
    float cc = sigm(ai) * tanh_f(ag);
    float hn = sigm(ao) * tanh_f(cc);
    float xv = xb[(size_t)s*H2_ + j];
    float dd = xv - hn;
    lacc += dd*dd; sxp += xv; x2p = fmaf(xv,xv,x2p);
    float delta = fabsf(hn - h);
    h = hn;
    __syncthreads();                      // all dot-reads of old hl done
    hl[j] = (_Float16)h;
    // race-free convergence vote: single counting barrier, uniform result
    if (__syncthreads_count(delta > EPS_CONV) == 0){ done = s+1; break; }
  }
  if (done < S_){
    size_t o = (size_t)b*H2_ + j;
    float rx = SX[o] - sxp, rx2 = SX2[o] - x2p;
    float rem = (float)(S_ - done);
    lacc += rx2 - 2.f*h*rx + rem*h*h;
  }
  red[j] = lacc;
  __syncthreads();
  for (int st=256; st>0; st>>=1){
    if (j < st) red[j] += red[j+st];
    __syncthreads();
  }
  if (j == 0) loss_b[b] = red[0];
}

// ---------------- output head ----------------
__global__ __launch_bounds__(256) void k_out(
    const float* __restrict__ SX, const float* __restrict__ SH,
    const float* __restrict__ outW, const float* __restrict__ outWb,
    const float* __restrict__ loss_b, float* __restrict__ out){
  int b = blockIdx.x, o = threadIdx.x;
  __shared__ float pooled[512];
  for (int d=o; d<512; d+=256){
    float v = SX[(size_t)b*H2_ + d];
    v += (d < E_) ? SH[(size_t)b*E_ + d] : SH[(size_t)(B_ + b)*E_ + (d - E_)];
    pooled[d] = v;
  }
  __syncthreads();
  const float4* w4 = (const float4*)(outW + (size_t)o*H2_);
  const float4* p4 = (const float4*)pooled;
  float acc = outWb[o];
  #pragma unroll 16
  for (int i=0;i<128;i++){
    float4 w = w4[i], p = p4[i];
    acc = fmaf(w.x,p.x,acc); acc = fmaf(w.y,p.y,acc);
    acc = fmaf(w.z,p.z,acc); acc = fmaf(w.w,p.w,acc);
  }
  out[(size_t)b*256 + o] = acc;
  if (b == 0 && o == 0){
    float L = 0.f;
    for (int i=0;i<B_;i++) L += loss_b[i];
    out[32768] = L / 33554432.f;
  }
}

extern "C" void kernel_launch(void* const* d_in, const int* in_sizes, int n_in,
                              void* d_out, int out_size, void* d_ws, size_t ws_size,
                              hipStream_t stream) {
  const float* X     = (const float*)d_in[0];
  const float* Wihf  = (const float*)d_in[1];
  const float* Whhf  = (const float*)d_in[2];
  const float* bihf  = (const float*)d_in[3];
  const float* bhhf  = (const float*)d_in[4];
  const float* Wihb  = (const float*)d_in[5];
  const float* Whhb  = (const float*)d_in[6];
  const float* bihb  = (const float*)d_in[7];
  const float* bhhb  = (const float*)d_in[8];
  const float* Wdec  = (const float*)d_in[9];
  const float* dbih  = (const float*)d_in[10];
  const float* dbhh  = (const float*)d_in[11];
  // d_in[12..15]: attW/attW_b/attU/attU_b are mathematically dead (softmax over size-1 axis)
  const float* outW  = (const float*)d_in[16];
  const float* outWb = (const float*)d_in[17];
  float* out = (float*)d_out;

  char* ws = (char*)d_ws;
  size_t off = 0;
  auto alloc = [&](size_t bytes){ void* p = ws + off; off += (bytes + 255) & ~(size_t)255; return p; };
  __hip_bfloat16* pre  = (__hip_bfloat16*)alloc((size_t)M_*DG_*2);   // 268 MB
  ushort* Wenc         = (ushort*)alloc((size_t)DG_*H2_*2);
  float* bsum          = (float*)alloc((size_t)DG_*4);
  uint8_t* whh8        = (uint8_t*)alloc((size_t)2*G_*E_);
  uint4* wdt           = (uint4*)alloc((size_t)64*DG_*16);
  float* bsumd         = (float*)alloc((size_t)DG_*4);
  float* SX            = (float*)alloc((size_t)B_*H2_*4);
  float* SX2           = (float*)alloc((size_t)B_*H2_*4);
  float* SH            = (float*)alloc((size_t)2*B_*E_*4);
  float* x0            = (float*)alloc((size_t)B_*H2_*4);
  float* loss_b        = (float*)alloc((size_t)B_*4);

  hipLaunchKernelGGL(k_prep_enc, dim3(DG_), dim3(512), 0, stream,
                     Wihf, Wihb, bihf, bhhf, bihb, bhhb, Wenc, bsum);
  hipLaunchKernelGGL(k_prep_whh, dim3(2*G_), dim3(E_), 0, stream, Whhf, Whhb, whh8);
  hipLaunchKernelGGL(k_prep_dec, dim3(DG_), dim3(64), 0, stream, Wdec, dbih, dbhh, wdt, bsumd);
  hipLaunchKernelGGL(k_xstat, dim3(B_), dim3(H2_), 0, stream, X, SX, SX2);
  hipLaunchKernelGGL(k_gemm_pre, dim3(16, 512), dim3(256), 0, stream, X, Wenc, bsum, pre);
  hipLaunchKernelGGL(k_enc_rec, dim3(256), dim3(512), 0, stream,
                     pre, whh8, SH, x0);
  hipLaunchKernelGGL(k_dec, dim3(B_), dim3(512), 0, stream, X, wdt, bsumd, x0, SX, SX2, loss_b);
  hipLaunchKernelGGL(k_out, dim3(B_), dim3(256), 0, stream, SX, SH, outW, outWb, loss_b, out);
}

// Round 7
// 15482.207 us; speedup vs baseline: 1.7679x; 1.7679x over previous
//
#include <hip/hip_runtime.h>
#include <hip/hip_bf16.h>
#include <hip/hip_fp16.h>
#include <stdint.h>

#define B_ 128
#define S_ 512
#define E_ 256
#define H2_ 512
#define G_ 1024      // 4*E
#define DG_ 2048     // 4*H2
#define M_ (B_*S_)   // 65536

typedef float f32x4 __attribute__((ext_vector_type(4)));
typedef short s16x8 __attribute__((ext_vector_type(8)));
typedef _Float16 h16x2 __attribute__((ext_vector_type(2)));

__device__ __forceinline__ float sigm(float x){ return 1.f/(1.f+__expf(-x)); }
__device__ __forceinline__ float tanh_f(float x){ return 1.f - 2.f/(__expf(2.f*x)+1.f); }

// ---------------- fp8 e4m3fn encode/decode ----------------
__device__ __forceinline__ uint32_t enc_e4m3(float f){
  uint32_t u = __float_as_uint(f);
  uint32_t s = (u >> 24) & 0x80u;
  float af = fabsf(f);
  if (!(af > 0.f)) return s;
  if (af >= 448.f) return s | 0x7Eu;
  int ex = (int)((u >> 23) & 0xFF) - 127;
  uint32_t man = u & 0x7FFFFFu;
  int bexp = ex + 7;
  if (bexp <= 0){
    uint32_t qi = (uint32_t)rintf(af * 512.f);
    if (qi > 8u) qi = 8u;
    return s | qi;
  }
  uint32_t keep = man >> 20;
  uint32_t rest = man & 0xFFFFFu;
  const uint32_t half = 0x80000u;
  if (rest > half || (rest == half && (keep & 1u))) keep++;
  if (keep == 8u){ keep = 0u; bexp++; }
  if (bexp >= 16) return s | 0x7Eu;
  if (bexp == 15 && keep == 7u) keep = 6u; // avoid NaN encoding
  return s | ((uint32_t)bexp << 3) | keep;
}

__device__ __forceinline__ float dec_e4m3(uint32_t byte){
  uint32_t s = (byte & 0x80u) << 24;
  uint32_t e = (byte >> 3) & 0xFu;
  uint32_t m = byte & 7u;
  float v;
  if (e == 0) v = (float)m * 0.001953125f;
  else v = __uint_as_float(((e + 120u) << 23) | (m << 20));
  return __uint_as_float(__float_as_uint(v) | s);
}

__device__ __forceinline__ void fp8x4_to_f32x4(uint32_t w, float* o){
#if __has_builtin(__builtin_amdgcn_cvt_pk_f32_fp8)
  auto lo = __builtin_amdgcn_cvt_pk_f32_fp8((int)w, false);
  auto hi = __builtin_amdgcn_cvt_pk_f32_fp8((int)w, true);
  o[0]=lo[0]; o[1]=lo[1]; o[2]=hi[0]; o[3]=hi[1];
#else
  o[0]=dec_e4m3(w & 0xFFu); o[1]=dec_e4m3((w>>8)&0xFFu);
  o[2]=dec_e4m3((w>>16)&0xFFu); o[3]=dec_e4m3(w>>24);
#endif
}

__device__ __forceinline__ float dot2_f16(uint32_t a, uint32_t b, float acc){
#if __has_builtin(__builtin_amdgcn_fdot2)
  return __builtin_amdgcn_fdot2(__builtin_bit_cast(h16x2,a), __builtin_bit_cast(h16x2,b), acc, false);
#else
  __half2 ah = __builtin_bit_cast(__half2, a), bh = __builtin_bit_cast(__half2, b);
  float2 af = __half22float2(ah), bf = __half22float2(bh);
  return fmaf(af.x, bf.x, fmaf(af.y, bf.y, acc));
#endif
}

// ---------------- weight prep ----------------
__global__ __launch_bounds__(512) void k_prep_enc(
    const float* __restrict__ wf, const float* __restrict__ wb,
    const float* __restrict__ bihf, const float* __restrict__ bhhf,
    const float* __restrict__ bihb, const float* __restrict__ bhhb,
    ushort* __restrict__ Wenc, float* __restrict__ bsum){
  int n = blockIdx.x, d = threadIdx.x;
  const float* src = (n < G_) ? (wf + (size_t)n*H2_) : (wb + (size_t)(n-G_)*H2_);
  __hip_bfloat16 h = __float2bfloat16(src[d]);
  Wenc[(size_t)n*H2_ + d] = __builtin_bit_cast(ushort, h);
  if (d == 0) bsum[n] = (n < G_) ? (bihf[n] + bhhf[n]) : (bihb[n-G_] + bhhb[n-G_]);
}

__global__ __launch_bounds__(256) void k_prep_whh(
    const float* __restrict__ whf, const float* __restrict__ whb, uint8_t* __restrict__ whh8){
  int r = blockIdx.x; int d = threadIdx.x;
  int dir = r >> 10, g = r & 1023;
  float v = dir ? whb[(size_t)g*E_ + d] : whf[(size_t)g*E_ + d];
  whh8[((size_t)dir*G_ + g)*E_ + d] = (uint8_t)enc_e4m3(v);
}

__global__ __launch_bounds__(64) void k_prep_dec(
    const float* __restrict__ wd, const float* __restrict__ bih, const float* __restrict__ bhh,
    uint4* __restrict__ wdt, float* __restrict__ bsumd){
  int row = blockIdx.x, u = threadIdx.x; // u in [0,64)
  const float* src = wd + (size_t)row*H2_ + u*8;
  union { _Float16 h[8]; uint4 q; } pk;
  #pragma unroll
  for (int i=0;i<8;i++) pk.h[i] = (_Float16)src[i];
  wdt[(size_t)u*DG_ + row] = pk.q;
  if (u == 0) bsumd[row] = bih[row] + bhh[row];
}

// ---------------- input stats ----------------
__global__ __launch_bounds__(512) void k_xstat(
    const float* __restrict__ X, float* __restrict__ SX, float* __restrict__ SX2){
  int b = blockIdx.x, d = threadIdx.x;
  const float* xb = X + (size_t)b*S_*H2_;
  float s=0.f, s2=0.f;
  for (int t=0;t<S_;++t){ float v = xb[(size_t)t*H2_ + d]; s += v; s2 = fmaf(v,v,s2); }
  SX[(size_t)b*H2_+d]=s; SX2[(size_t)b*H2_+d]=s2;
}

// ---------------- pre-GEMM: pre[m][n] = X[m][:] . Wenc[n][:] + bsum[n] ----------------
__global__ __launch_bounds__(256) void k_gemm_pre(
    const float* __restrict__ X, const ushort* __restrict__ Wenc,
    const float* __restrict__ bsum, __hip_bfloat16* __restrict__ pre){
  __shared__ ushort As[128][64];
  __shared__ ushort Bs[128][64];
  int n0 = blockIdx.x * 128, m0 = blockIdx.y * 128;
  int tid = threadIdx.x, lane = tid & 63, wid = tid >> 6;
  int wr = wid >> 1, wc = wid & 1;
  f32x4 acc[4][4] = {};
  for (int kt=0; kt<8; ++kt){
    int k0 = kt*64;
    #pragma unroll
    for (int it=0; it<4; ++it){
      int slot = tid + it*256;
      int r = slot >> 3, c8 = (slot & 7)*8;
      const float* ap = X + (size_t)(m0+r)*512 + k0 + c8;
      float4 a0 = *(const float4*)ap;
      float4 a1 = *(const float4*)(ap+4);
      union { __hip_bfloat16 h[8]; uint4 q; } pk;
      pk.h[0]=__float2bfloat16(a0.x); pk.h[1]=__float2bfloat16(a0.y);
      pk.h[2]=__float2bfloat16(a0.z); pk.h[3]=__float2bfloat16(a0.w);
      pk.h[4]=__float2bfloat16(a1.x); pk.h[5]=__float2bfloat16(a1.y);
      pk.h[6]=__float2bfloat16(a1.z); pk.h[7]=__float2bfloat16(a1.w);
      *(uint4*)&As[r][c8] = pk.q;
      *(uint4*)&Bs[r][c8] = *(const uint4*)(Wenc + (size_t)(n0+r)*512 + k0 + c8);
    }
    __syncthreads();
    #pragma unroll
    for (int kk=0; kk<2; ++kk){
      int krow = kk*32 + (lane>>4)*8;
      s16x8 af[4], bf[4];
      #pragma unroll
      for (int mi=0;mi<4;mi++) af[mi] = *(const s16x8*)&As[wr*64+mi*16+(lane&15)][krow];
      #pragma unroll
      for (int ni=0;ni<4;ni++) bf[ni] = *(const s16x8*)&Bs[wc*64+ni*16+(lane&15)][krow];
      #pragma unroll
      for (int mi=0;mi<4;mi++){
        #pragma unroll
        for (int ni=0;ni<4;ni++)
          acc[mi][ni] = __builtin_amdgcn_mfma_f32_16x16x32_bf16(af[mi], bf[ni], acc[mi][ni], 0,0,0);
      }
    }
    __syncthreads();
  }
  #pragma unroll
  for (int ni=0; ni<4; ++ni){
    int n = n0 + wc*64 + ni*16 + (lane&15);
    float bs = bsum[n];
    #pragma unroll
    for (int mi=0; mi<4; ++mi){
      int mb = m0 + wr*64 + mi*16 + (lane>>4)*4;
      #pragma unroll
      for (int r2=0;r2<4;r2++)
        pre[(size_t)(mb+r2)*DG_ + n] = __float2bfloat16(acc[mi][ni][r2] + bs);
    }
  }
}

// ---------------- encoder recurrence v7 ----------------
// v6 dataflow (thread j owns full k=256 of rowA=j [global, L2-resident] and
// rowB=j+512 [LDS]), but with ANTI-SPILL scaffolding:
//  * base indices laundered per s-iteration via asm (defeats LICM hoisting of
//    the 32 loop-invariant weight loads -> no loop-carried weight registers)
//  * explicit software pipeline: named rotating regs, global depth-3, LDS
//    depth-2, sched_barrier(0) after each chunk (max ~5 uint4 in flight)
__global__ __launch_bounds__(512) void k_enc_rec(
    const __hip_bfloat16* __restrict__ pre, const uint8_t* __restrict__ whh8,
    float* __restrict__ SH, float* __restrict__ x0){
  int wg = blockIdx.x;
  int dir = wg >> 7, b = wg & 127;
  int j = threadIdx.x;
  __shared__ float hbuf[2][256];
  __shared__ float abuf[256];
  __shared__ uint4 wlds[16*512];   // 128 KB

  // stage g,o rows into LDS: thread j stages gate row 512+j
  {
    const uint4* src = (const uint4*)(whh8 + ((size_t)dir*G_ + 512 + j)*E_);
    #pragma unroll
    for (int u=0; u<16; ++u) wlds[u*512 + j] = src[u];
  }
  if (j < 256) hbuf[0][j] = 0.f;
  float c = 0.f, sh = 0.f;
  const __hip_bfloat16* preB = pre + ((size_t)b*S_)*DG_ + dir*G_;
  int t0 = dir ? (S_-1) : 0;
  float p0 = __bfloat162float(preB[(size_t)t0*DG_ + j]);
  float p1 = __bfloat162float(preB[(size_t)t0*DG_ + j + 512]);
  __syncthreads();

#define WORD4(WA, WB, HI) do { \
    float4 hv = h4[HI]; \
    float da[4], db[4]; \
    fp8x4_to_f32x4(WA, da); fp8x4_to_f32x4(WB, db); \
    a0 = fmaf(da[0],hv.x,a0); a0 = fmaf(da[1],hv.y,a0); \
    a0 = fmaf(da[2],hv.z,a0); a0 = fmaf(da[3],hv.w,a0); \
    a1 = fmaf(db[0],hv.x,a1); a1 = fmaf(db[1],hv.y,a1); \
    a1 = fmaf(db[2],hv.z,a1); a1 = fmaf(db[3],hv.w,a1); \
  } while(0)
#define PROC(WA, WB, U) do { \
    WORD4((WA).x, (WB).x, (U)*4+0); WORD4((WA).y, (WB).y, (U)*4+1); \
    WORD4((WA).z, (WB).z, (U)*4+2); WORD4((WA).w, (WB).w, (U)*4+3); \
  } while(0)
// chunk U: prefetch global g[U+2] into ANN, LDS w[U+1] into BN, process (AC,BC)
#define CH(U, AC, ANN, BC, BN, LA, LB) do { \
    if (LA) ANN = gait[(U)+2]; \
    if (LB) BN = wlit[((U)+1)*512]; \
    PROC(AC, BC, U); \
    __builtin_amdgcn_sched_barrier(0); \
  } while(0)

  int pb = 0;
  for (int s=0; s<S_; ++s){
    // launder base indices: redefined every iteration -> LICM cannot hoist
    // the dependent weight loads out of the s-loop.
    uint32_t rA = (uint32_t)dir*G_ + (uint32_t)j;   // global rowA index
    uint32_t lj = (uint32_t)j;                      // LDS column index
    asm volatile("" : "+v"(rA), "+v"(lj));
    const uint4* gait = (const uint4*)(whh8 + (size_t)rA * E_);
    const uint4* wlit = wlds + lj;

    float a0 = p0, a1 = p1;                 // pre-activations folded in
    const float4* h4 = (const float4*)hbuf[pb];

    uint4 A0 = gait[0], A1 = gait[1], A2;
    uint4 B0 = wlit[0], B1;
    CH(0,  A0, A2, B0, B1, 1, 1);
    CH(1,  A1, A0, B1, B0, 1, 1);
    CH(2,  A2, A1, B0, B1, 1, 1);
    CH(3,  A0, A2, B1, B0, 1, 1);
    CH(4,  A1, A0, B0, B1, 1, 1);
    CH(5,  A2, A1, B1, B0, 1, 1);
    CH(6,  A0, A2, B0, B1, 1, 1);
    CH(7,  A1, A0, B1, B0, 1, 1);
    CH(8,  A2, A1, B0, B1, 1, 1);
    CH(9,  A0, A2, B1, B0, 1, 1);
    CH(10, A1, A0, B0, B1, 1, 1);
    CH(11, A2, A1, B1, B0, 1, 1);
    CH(12, A0, A2, B0, B1, 1, 1);
    CH(13, A1, A0, B1, B0, 1, 1);
    CH(14, A2, A1, B0, B1, 0, 1);
    CH(15, A0, A0, B1, B0, 0, 0);

    // prefetch next step's pre
    if (s+1 < S_){
      int tn = dir ? (S_-2-s) : (s+1);
      p0 = __bfloat162float(preB[(size_t)tn*DG_ + j]);
      p1 = __bfloat162float(preB[(size_t)tn*DG_ + j + 512]);
    }
    if (j < 256) abuf[j] = sigm(a0) * tanh_f(a1);   // sig(i)*tanh(g)
    __syncthreads();
    if (j >= 256){
      int jj = j - 256;
      c = sigm(a0)*c + abuf[jj];                     // sig(f)*c + sig(i)*tanh(g)
      float hn = sigm(a1)*tanh_f(c);                 // sig(o)*tanh(c)
      hbuf[pb^1][jj] = hn;
      sh += hn;
      if ((dir==0 && s==S_-1) || (dir==1 && s==0))
        x0[(size_t)b*H2_ + dir*E_ + jj] = hn;
    }
    __syncthreads();
    pb ^= 1;
  }
#undef CH
#undef PROC
#undef WORD4
  if (j >= 256) SH[((size_t)dir*B_ + b)*E_ + (j-256)] = sh;
}

// ---------------- decoder + ae_loss: 128 wgs = b, 512 thr = hidden dim ----------------
#define EPS_CONV 2e-6f
__global__ __launch_bounds__(512) void k_dec(
    const float* __restrict__ X, const uint4* __restrict__ wdt,
    const float* __restrict__ bsumd, const float* __restrict__ x0,
    const float* __restrict__ SX, const float* __restrict__ SX2,
    float* __restrict__ loss_b){
  int b = blockIdx.x, j = threadIdx.x;
  __shared__ _Float16 hl[512];
  __shared__ float red[512];
  float h = x0[(size_t)b*H2_ + j];
  hl[j] = (_Float16)h;
  float bi = bsumd[j], bg = bsumd[j+1024], bo = bsumd[j+1536];
  float sxp = 0.f, x2p = 0.f, lacc = 0.f;
  const float* xb = X + (size_t)b*S_*H2_;
  int done = S_;
  __syncthreads();
  for (int s=0; s<S_; ++s){
    float ai = bi, ag = bg, ao = bo;
    const uint4* hp = (const uint4*)hl;
    const uint4* wi = wdt + j;
    const uint4* wgp = wdt + j + 1024;
    const uint4* wo = wdt + j + 1536;
    #pragma unroll 8
    for (int u=0; u<64; ++u){
      uint4 hv = hp[u];
      uint4 a = wi[(size_t)u*DG_];
      uint4 g = wgp[(size_t)u*DG_];
      uint4 o = wo[(size_t)u*DG_];
      ai = dot2_f16(a.x, hv.x, ai); ai = dot2_f16(a.y, hv.y, ai);
      ai = dot2_f16(a.z, hv.z, ai); ai = dot2_f16(a.w, hv.w, ai);
      ag = dot2_f16(g.x, hv.x, ag); ag = dot2_f16(g.y, hv.y, ag);
      ag = dot2_f16(g.z, hv.z, ag); ag = dot2_f16(g.w, hv.w, ag);
      ao = dot2_f16(o.x, hv.x, ao); ao = dot2_f16(o.y, hv.y, ao);
      ao = dot2_f16(o.z, hv.z, ao); ao = dot2_f16(o.w, hv.w, ao);
    }
    float cc = sigm(ai) * tanh_f(ag);
    float hn = sigm(ao) * tanh_f(cc);
    float xv = xb[(size_t)s*H2_ + j];
    float dd = xv - hn;
    lacc += dd*dd; sxp += xv; x2p = fmaf(xv,xv,x2p);
    float delta = fabsf(hn - h);
    h = hn;
    __syncthreads();                      // all dot-reads of old hl done
    hl[j] = (_Float16)h;
    // race-free convergence vote: single counting barrier, uniform result
    if (__syncthreads_count(delta > EPS_CONV) == 0){ done = s+1; break; }
  }
  if (done < S_){
    size_t o = (size_t)b*H2_ + j;
    float rx = SX[o] - sxp, rx2 = SX2[o] - x2p;
    float rem = (float)(S_ - done);
    lacc += rx2 - 2.f*h*rx + rem*h*h;
  }
  red[j] = lacc;
  __syncthreads();
  for (int st=256; st>0; st>>=1){
    if (j < st) red[j] += red[j+st];
    __syncthreads();
  }
  if (j == 0) loss_b[b] = red[0];
}

// ---------------- output head ----------------
__global__ __launch_bounds__(256) void k_out(
    const float* __restrict__ SX, const float* __restrict__ SH,
    const float* __restrict__ outW, const float* __restrict__ outWb,
    const float* __restrict__ loss_b, float* __restrict__ out){
  int b = blockIdx.x, o = threadIdx.x;
  __shared__ float pooled[512];
  for (int d=o; d<512; d+=256){
    float v = SX[(size_t)b*H2_ + d];
    v += (d < E_) ? SH[(size_t)b*E_ + d] : SH[(size_t)(B_ + b)*E_ + (d - E_)];
    pooled[d] = v;
  }
  __syncthreads();
  const float4* w4 = (const float4*)(outW + (size_t)o*H2_);
  const float4* p4 = (const float4*)pooled;
  float acc = outWb[o];
  #pragma unroll 16
  for (int i=0;i<128;i++){
    float4 w = w4[i], p = p4[i];
    acc = fmaf(w.x,p.x,acc); acc = fmaf(w.y,p.y,acc);
    acc = fmaf(w.z,p.z,acc); acc = fmaf(w.w,p.w,acc);
  }
  out[(size_t)b*256 + o] = acc;
  if (b == 0 && o == 0){
    float L = 0.f;
    for (int i=0;i<B_;i++) L += loss_b[i];
    out[32768] = L / 33554432.f;
  }
}

extern "C" void kernel_launch(void* const* d_in, const int* in_sizes, int n_in,
                              void* d_out, int out_size, void* d_ws, size_t ws_size,
                              hipStream_t stream) {
  const float* X     = (const float*)d_in[0];
  const float* Wihf  = (const float*)d_in[1];
  const float* Whhf  = (const float*)d_in[2];
  const float* bihf  = (const float*)d_in[3];
  const float* bhhf  = (const float*)d_in[4];
  const float* Wihb  = (const float*)d_in[5];
  const float* Whhb  = (const float*)d_in[6];
  const float* bihb  = (const float*)d_in[7];
  const float* bhhb  = (const float*)d_in[8];
  const float* Wdec  = (const float*)d_in[9];
  const float* dbih  = (const float*)d_in[10];
  const float* dbhh  = (const float*)d_in[11];
  // d_in[12..15]: attW/attW_b/attU/attU_b are mathematically dead (softmax over size-1 axis)
  const float* outW  = (const float*)d_in[16];
  const float* outWb = (const float*)d_in[17];
  float* out = (float*)d_out;

  char* ws = (char*)d_ws;
  size_t off = 0;
  auto alloc = [&](size_t bytes){ void* p = ws + off; off += (bytes + 255) & ~(size_t)255; return p; };
  __hip_bfloat16* pre  = (__hip_bfloat16*)alloc((size_t)M_*DG_*2);   // 268 MB
  ushort* Wenc         = (ushort*)alloc((size_t)DG_*H2_*2);
  float* bsum          = (float*)alloc((size_t)DG_*4);
  uint8_t* whh8        = (uint8_t*)alloc((size_t)2*G_*E_);
  uint4* wdt           = (uint4*)alloc((size_t)64*DG_*16);
  float* bsumd         = (float*)alloc((size_t)DG_*4);
  float* SX            = (float*)alloc((size_t)B_*H2_*4);
  float* SX2           = (float*)alloc((size_t)B_*H2_*4);
  float* SH            = (float*)alloc((size_t)2*B_*E_*4);
  float* x0            = (float*)alloc((size_t)B_*H2_*4);
  float* loss_b        = (float*)alloc((size_t)B_*4);

  hipLaunchKernelGGL(k_prep_enc, dim3(DG_), dim3(512), 0, stream,
                     Wihf, Wihb, bihf, bhhf, bihb, bhhb, Wenc, bsum);
  hipLaunchKernelGGL(k_prep_whh, dim3(2*G_), dim3(E_), 0, stream, Whhf, Whhb, whh8);
  hipLaunchKernelGGL(k_prep_dec, dim3(DG_), dim3(64), 0, stream, Wdec, dbih, dbhh, wdt, bsumd);
  hipLaunchKernelGGL(k_xstat, dim3(B_), dim3(H2_), 0, stream, X, SX, SX2);
  hipLaunchKernelGGL(k_gemm_pre, dim3(16, 512), dim3(256), 0, stream, X, Wenc, bsum, pre);
  hipLaunchKernelGGL(k_enc_rec, dim3(256), dim3(512), 0, stream,
                     pre, whh8, SH, x0);
  hipLaunchKernelGGL(k_dec, dim3(B_), dim3(512), 0, stream, X, wdt, bsumd, x0, SX, SX2, loss_b);
  hipLaunchKernelGGL(k_out, dim3(B_), dim3(256), 0, stream, SX, SH, outW, outWb, loss_b, out);
}

// Round 8
// 9735.138 us; speedup vs baseline: 2.8115x; 1.5903x over previous
//
#include <hip/hip_runtime.h>
#include <hip/hip_bf16.h>
#include <hip/hip_fp16.h>
#include <stdint.h>

#define B_ 128
#define S_ 512
#define E_ 256
#define H2_ 512
#define G_ 1024      // 4*E
#define DG_ 2048     // 4*H2
#define M_ (B_*S_)   // 65536

typedef float f32x4 __attribute__((ext_vector_type(4)));
typedef short s16x8 __attribute__((ext_vector_type(8)));
typedef _Float16 h16x2 __attribute__((ext_vector_type(2)));

__device__ __forceinline__ float sigm(float x){ return 1.f/(1.f+__expf(-x)); }
__device__ __forceinline__ float tanh_f(float x){ return 1.f - 2.f/(__expf(2.f*x)+1.f); }

__device__ __forceinline__ float dot2_f16(uint32_t a, uint32_t b, float acc){
#if __has_builtin(__builtin_amdgcn_fdot2)
  return __builtin_amdgcn_fdot2(__builtin_bit_cast(h16x2,a), __builtin_bit_cast(h16x2,b), acc, false);
#else
  __half2 ah = __builtin_bit_cast(__half2, a), bh = __builtin_bit_cast(__half2, b);
  float2 af = __half22float2(ah), bf = __half22float2(bh);
  return fmaf(af.x, bf.x, fmaf(af.y, bf.y, acc));
#endif
}

// ---------------- weight prep ----------------
__global__ __launch_bounds__(512) void k_prep_enc(
    const float* __restrict__ wf, const float* __restrict__ wb,
    const float* __restrict__ bihf, const float* __restrict__ bhhf,
    const float* __restrict__ bihb, const float* __restrict__ bhhb,
    ushort* __restrict__ Wenc, float* __restrict__ bsum){
  int n = blockIdx.x, d = threadIdx.x;
  const float* src = (n < G_) ? (wf + (size_t)n*H2_) : (wb + (size_t)(n-G_)*H2_);
  __hip_bfloat16 h = __float2bfloat16(src[d]);
  Wenc[(size_t)n*H2_ + d] = __builtin_bit_cast(ushort, h);
  if (d == 0) bsum[n] = (n < G_) ? (bihf[n] + bhhf[n]) : (bihb[n-G_] + bhhb[n-G_]);
}

// Whh as bf16, [dir][1024 gate-rows][256 k]
__global__ __launch_bounds__(256) void k_prep_whh_bf(
    const float* __restrict__ whf, const float* __restrict__ whb, ushort* __restrict__ wt){
  int r = blockIdx.x;      // 0..2047 = dir*1024 + n
  int d = threadIdx.x;     // 0..255
  int dir = r >> 10, n = r & 1023;
  float v = dir ? whb[(size_t)n*E_ + d] : whf[(size_t)n*E_ + d];
  __hip_bfloat16 h = __float2bfloat16(v);
  wt[(size_t)r*E_ + d] = __builtin_bit_cast(ushort, h);
}

__global__ __launch_bounds__(64) void k_prep_dec(
    const float* __restrict__ wd, const float* __restrict__ bih, const float* __restrict__ bhh,
    uint4* __restrict__ wdt, float* __restrict__ bsumd){
  int row = blockIdx.x, u = threadIdx.x; // u in [0,64)
  const float* src = wd + (size_t)row*H2_ + u*8;
  union { _Float16 h[8]; uint4 q; } pk;
  #pragma unroll
  for (int i=0;i<8;i++) pk.h[i] = (_Float16)src[i];
  wdt[(size_t)u*DG_ + row] = pk.q;
  if (u == 0) bsumd[row] = bih[row] + bhh[row];
}

// ---------------- input stats ----------------
__global__ __launch_bounds__(512) void k_xstat(
    const float* __restrict__ X, float* __restrict__ SX, float* __restrict__ SX2){
  int b = blockIdx.x, d = threadIdx.x;
  const float* xb = X + (size_t)b*S_*H2_;
  float s=0.f, s2=0.f;
  for (int t=0;t<S_;++t){ float v = xb[(size_t)t*H2_ + d]; s += v; s2 = fmaf(v,v,s2); }
  SX[(size_t)b*H2_+d]=s; SX2[(size_t)b*H2_+d]=s2;
}

// ---------------- pre-GEMM: pre[m][n] = X[m][:] . Wenc[n][:] + bsum[n] ----------------
__global__ __launch_bounds__(256) void k_gemm_pre(
    const float* __restrict__ X, const ushort* __restrict__ Wenc,
    const float* __restrict__ bsum, __hip_bfloat16* __restrict__ pre){
  __shared__ ushort As[128][64];
  __shared__ ushort Bs[128][64];
  int n0 = blockIdx.x * 128, m0 = blockIdx.y * 128;
  int tid = threadIdx.x, lane = tid & 63, wid = tid >> 6;
  int wr = wid >> 1, wc = wid & 1;
  f32x4 acc[4][4] = {};
  for (int kt=0; kt<8; ++kt){
    int k0 = kt*64;
    #pragma unroll
    for (int it=0; it<4; ++it){
      int slot = tid + it*256;
      int r = slot >> 3, c8 = (slot & 7)*8;
      const float* ap = X + (size_t)(m0+r)*512 + k0 + c8;
      float4 a0 = *(const float4*)ap;
      float4 a1 = *(const float4*)(ap+4);
      union { __hip_bfloat16 h[8]; uint4 q; } pk;
      pk.h[0]=__float2bfloat16(a0.x); pk.h[1]=__float2bfloat16(a0.y);
      pk.h[2]=__float2bfloat16(a0.z); pk.h[3]=__float2bfloat16(a0.w);
      pk.h[4]=__float2bfloat16(a1.x); pk.h[5]=__float2bfloat16(a1.y);
      pk.h[6]=__float2bfloat16(a1.z); pk.h[7]=__float2bfloat16(a1.w);
      *(uint4*)&As[r][c8] = pk.q;
      *(uint4*)&Bs[r][c8] = *(const uint4*)(Wenc + (size_t)(n0+r)*512 + k0 + c8);
    }
    __syncthreads();
    #pragma unroll
    for (int kk=0; kk<2; ++kk){
      int krow = kk*32 + (lane>>4)*8;
      s16x8 af[4], bf[4];
      #pragma unroll
      for (int mi=0;mi<4;mi++) af[mi] = *(const s16x8*)&As[wr*64+mi*16+(lane&15)][krow];
      #pragma unroll
      for (int ni=0;ni<4;ni++) bf[ni] = *(const s16x8*)&Bs[wc*64+ni*16+(lane&15)][krow];
      #pragma unroll
      for (int mi=0;mi<4;mi++){
        #pragma unroll
        for (int ni=0;ni<4;ni++)
          acc[mi][ni] = __builtin_amdgcn_mfma_f32_16x16x32_bf16(af[mi], bf[ni], acc[mi][ni], 0,0,0);
      }
    }
    __syncthreads();
  }
  #pragma unroll
  for (int ni=0; ni<4; ++ni){
    int n = n0 + wc*64 + ni*16 + (lane&15);
    float bs = bsum[n];
    #pragma unroll
    for (int mi=0; mi<4; ++mi){
      int mb = m0 + wr*64 + mi*16 + (lane>>4)*4;
      #pragma unroll
      for (int r2=0;r2<4;r2++)
        pre[(size_t)(mb+r2)*DG_ + n] = __float2bfloat16(acc[mi][ni][r2] + bs);
    }
  }
}

// ---------------- encoder recurrence v8: MFMA GEMM per step ----------------
// 16 wgs; wg owns 16 chains (chain = wg*16+m; dir = wg>>3, b = (wg&7)*16+m).
// Per step: C[16 chains][1024 gates] = h[16][256] . Whh^T via 8 waves x
// (8 tiles x 8 K-slices) mfma_f32_16x16x32_bf16. B-frags streamed from
// L2-resident bf16 Whh (512 KB/dir; 2 wgs/XCD). A-frags from LDS hbf.
// Epilogue: gbuf stride-17 (conflict-free combine reads), pre staged to pbuf.
// Combine: thread t owns (m=t>>5, units u=(t&31)+32r); c-state in 8 VGPRs.
__global__ __launch_bounds__(512) void k_enc_mfma(
    const __hip_bfloat16* __restrict__ pre, const ushort* __restrict__ wt,
    float* __restrict__ SH, float* __restrict__ x0){
  int wg = blockIdx.x;            // 0..15
  int dir = wg >> 3;
  int b0 = (wg & 7) * 16;
  int t = threadIdx.x, lane = t & 63, wid = t >> 6;
  __shared__ __align__(16) float  gbuf[1024*17];   // 68 KB
  __shared__ __align__(16) ushort hbf[16*264];     // 8.25 KB (264 = pad for banks)
  __shared__ __align__(16) ushort pbuf[16*1024];   // 32 KB

  for (int i = t; i < 16*264; i += 512) hbf[i] = 0;

  int mc = t >> 5, ub = t & 31;        // combine role
  float c_st[8] = {0,0,0,0,0,0,0,0};
  float sumh[8] = {0,0,0,0,0,0,0,0};

  const ushort* WdT = wt + (size_t)dir * G_ * E_;
  int n0w  = wid * 128;                // wave's gate-row range
  int frow = lane & 15;
  int fk   = (lane >> 4) * 8;
  int sm = t >> 5;                     // staging: chain m
  int sc = (t & 31) * 32;              // staging: col offset (bf16 units)
  __syncthreads();

  for (int s = 0; s < S_; ++s){
    // ---- P1: MFMA ----
    const ushort* Wl = WdT;
    asm volatile("" : "+v"(Wl));       // anti-LICM: W loads re-issue each step (L2 hits)
    s16x8 a[8];
    #pragma unroll
    for (int kk=0; kk<8; ++kk)
      a[kk] = *(const s16x8*)&hbf[frow*264 + kk*32 + fk];
    f32x4 acc[8] = {};
    #pragma unroll
    for (int tl=0; tl<8; ++tl){
      const ushort* wb = Wl + (size_t)(n0w + tl*16 + frow)*E_ + fk;
      #pragma unroll
      for (int kk=0; kk<8; ++kk){
        s16x8 bf = *(const s16x8*)(wb + kk*32);
        acc[tl] = __builtin_amdgcn_mfma_f32_16x16x32_bf16(a[kk], bf, acc[tl], 0,0,0);
      }
    }
    // issue pre-tile loads (consumed via pbuf in P3; latency hides under stores)
    int ts = dir ? (S_-1 - s) : s;
    const uint4* psrc = (const uint4*)(pre + ((size_t)((b0+sm)*S_ + ts))*DG_ + dir*G_ + sc);
    uint4 pv0 = psrc[0], pv1 = psrc[1], pv2 = psrc[2], pv3 = psrc[3];
    // ---- P2: C -> gbuf (stride 17), pre -> pbuf ----
    #pragma unroll
    for (int tl=0; tl<8; ++tl){
      int n = n0w + tl*16 + frow;
      int mb = (lane>>4)*4;
      gbuf[n*17 + mb + 0] = acc[tl][0];
      gbuf[n*17 + mb + 1] = acc[tl][1];
      gbuf[n*17 + mb + 2] = acc[tl][2];
      gbuf[n*17 + mb + 3] = acc[tl][3];
    }
    { uint4* pd = (uint4*)&pbuf[sm*1024 + sc];
      pd[0]=pv0; pd[1]=pv1; pd[2]=pv2; pd[3]=pv3; }
    __syncthreads();
    // ---- P3: gates + state update ----
    int wx0 = (dir==0 && s==S_-1) || (dir==1 && s==0);
    #pragma unroll
    for (int r=0; r<8; ++r){
      int u = ub + r*32;
      float gi = gbuf[u*17 + mc];
      float gf = gbuf[(u+256)*17 + mc];
      float gg = gbuf[(u+512)*17 + mc];
      float go = gbuf[(u+768)*17 + mc];
      gi += __bfloat162float(__builtin_bit_cast(__hip_bfloat16, pbuf[mc*1024 + u]));
      gf += __bfloat162float(__builtin_bit_cast(__hip_bfloat16, pbuf[mc*1024 + u + 256]));
      gg += __bfloat162float(__builtin_bit_cast(__hip_bfloat16, pbuf[mc*1024 + u + 512]));
      go += __bfloat162float(__builtin_bit_cast(__hip_bfloat16, pbuf[mc*1024 + u + 768]));
      float cn = sigm(gf)*c_st[r] + sigm(gi)*tanh_f(gg);
      float hn = sigm(go)*tanh_f(cn);
      c_st[r] = cn;
      sumh[r] += hn;
      __hip_bfloat16 hb = __float2bfloat16(hn);
      hbf[mc*264 + u] = __builtin_bit_cast(ushort, hb);
      if (wx0) x0[(size_t)(b0+mc)*H2_ + dir*E_ + u] = hn;
    }
    __syncthreads();
  }
  #pragma unroll
  for (int r=0; r<8; ++r){
    int u = ub + r*32;
    SH[((size_t)dir*B_ + (b0+mc))*E_ + u] = sumh[r];
  }
}

// ---------------- decoder + ae_loss: 128 wgs = b, 512 thr = hidden dim ----------------
#define EPS_CONV 2e-6f
__global__ __launch_bounds__(512) void k_dec(
    const float* __restrict__ X, const uint4* __restrict__ wdt,
    const float* __restrict__ bsumd, const float* __restrict__ x0,
    const float* __restrict__ SX, const float* __restrict__ SX2,
    float* __restrict__ loss_b){
  int b = blockIdx.x, j = threadIdx.x;
  __shared__ _Float16 hl[512];
  __shared__ float red[512];
  float h = x0[(size_t)b*H2_ + j];
  hl[j] = (_Float16)h;
  float bi = bsumd[j], bg = bsumd[j+1024], bo = bsumd[j+1536];
  float sxp = 0.f, x2p = 0.f, lacc = 0.f;
  const float* xb = X + (size_t)b*S_*H2_;
  int done = S_;
  __syncthreads();
  for (int s=0; s<S_; ++s){
    float ai = bi, ag = bg, ao = bo;
    const uint4* hp = (const uint4*)hl;
    const uint4* wi = wdt + j;
    const uint4* wgp = wdt + j + 1024;
    const uint4* wo = wdt + j + 1536;
    #pragma unroll 8
    for (int u=0; u<64; ++u){
      uint4 hv = hp[u];
      uint4 a = wi[(size_t)u*DG_];
      uint4 g = wgp[(size_t)u*DG_];
      uint4 o = wo[(size_t)u*DG_];
      ai = dot2_f16(a.x, hv.x, ai); ai = dot2_f16(a.y, hv.y, ai);
      ai = dot2_f16(a.z, hv.z, ai); ai = dot2_f16(a.w, hv.w, ai);
      ag = dot2_f16(g.x, hv.x, ag); ag = dot2_f16(g.y, hv.y, ag);
      ag = dot2_f16(g.z, hv.z, ag); ag = dot2_f16(g.w, hv.w, ag);
      ao = dot2_f16(o.x, hv.x, ao); ao = dot2_f16(o.y, hv.y, ao);
      ao = dot2_f16(o.z, hv.z, ao); ao = dot2_f16(o.w, hv.w, ao);
    }
    float cc = sigm(ai) * tanh_f(ag);
    float hn = sigm(ao) * tanh_f(cc);
    float xv = xb[(size_t)s*H2_ + j];
    float dd = xv - hn;
    lacc += dd*dd; sxp += xv; x2p = fmaf(xv,xv,x2p);
    float delta = fabsf(hn - h);
    h = hn;
    __syncthreads();                      // all dot-reads of old hl done
    hl[j] = (_Float16)h;
    // race-free convergence vote: single counting barrier, uniform result
    if (__syncthreads_count(delta > EPS_CONV) == 0){ done = s+1; break; }
  }
  if (done < S_){
    size_t o = (size_t)b*H2_ + j;
    float rx = SX[o] - sxp, rx2 = SX2[o] - x2p;
    float rem = (float)(S_ - done);
    lacc += rx2 - 2.f*h*rx + rem*h*h;
  }
  red[j] = lacc;
  __syncthreads();
  for (int st=256; st>0; st>>=1){
    if (j < st) red[j] += red[j+st];
    __syncthreads();
  }
  if (j == 0) loss_b[b] = red[0];
}

// ---------------- output head ----------------
__global__ __launch_bounds__(256) void k_out(
    const float* __restrict__ SX, const float* __restrict__ SH,
    const float* __restrict__ outW, const float* __restrict__ outWb,
    const float* __restrict__ loss_b, float* __restrict__ out){
  int b = blockIdx.x, o = threadIdx.x;
  __shared__ float pooled[512];
  for (int d=o; d<512; d+=256){
    float v = SX[(size_t)b*H2_ + d];
    v += (d < E_) ? SH[(size_t)b*E_ + d] : SH[(size_t)(B_ + b)*E_ + (d - E_)];
    pooled[d] = v;
  }
  __syncthreads();
  const float4* w4 = (const float4*)(outW + (size_t)o*H2_);
  const float4* p4 = (const float4*)pooled;
  float acc = outWb[o];
  #pragma unroll 16
  for (int i=0;i<128;i++){
    float4 w = w4[i], p = p4[i];
    acc = fmaf(w.x,p.x,acc); acc = fmaf(w.y,p.y,acc);
    acc = fmaf(w.z,p.z,acc); acc = fmaf(w.w,p.w,acc);
  }
  out[(size_t)b*256 + o] = acc;
  if (b == 0 && o == 0){
    float L = 0.f;
    for (int i=0;i<B_;i++) L += loss_b[i];
    out[32768] = L / 33554432.f;
  }
}

extern "C" void kernel_launch(void* const* d_in, const int* in_sizes, int n_in,
                              void* d_out, int out_size, void* d_ws, size_t ws_size,
                              hipStream_t stream) {
  const float* X     = (const float*)d_in[0];
  const float* Wihf  = (const float*)d_in[1];
  const float* Whhf  = (const float*)d_in[2];
  const float* bihf  = (const float*)d_in[3];
  const float* bhhf  = (const float*)d_in[4];
  const float* Wihb  = (const float*)d_in[5];
  const float* Whhb  = (const float*)d_in[6];
  const float* bihb  = (const float*)d_in[7];
  const float* bhhb  = (const float*)d_in[8];
  const float* Wdec  = (const float*)d_in[9];
  const float* dbih  = (const float*)d_in[10];
  const float* dbhh  = (const float*)d_in[11];
  // d_in[12..15]: attW/attW_b/attU/attU_b are mathematically dead (softmax over size-1 axis)
  const float* outW  = (const float*)d_in[16];
  const float* outWb = (const float*)d_in[17];
  float* out = (float*)d_out;

  char* ws = (char*)d_ws;
  size_t off = 0;
  auto alloc = [&](size_t bytes){ void* p = ws + off; off += (bytes + 255) & ~(size_t)255; return p; };
  __hip_bfloat16* pre  = (__hip_bfloat16*)alloc((size_t)M_*DG_*2);   // 268 MB
  ushort* Wenc         = (ushort*)alloc((size_t)DG_*H2_*2);
  float* bsum          = (float*)alloc((size_t)DG_*4);
  ushort* wtbf         = (ushort*)alloc((size_t)2*G_*E_*2);          // Whh bf16 [dir][n][k]
  uint4* wdt           = (uint4*)alloc((size_t)64*DG_*16);
  float* bsumd         = (float*)alloc((size_t)DG_*4);
  float* SX            = (float*)alloc((size_t)B_*H2_*4);
  float* SX2           = (float*)alloc((size_t)B_*H2_*4);
  float* SH            = (float*)alloc((size_t)2*B_*E_*4);
  float* x0            = (float*)alloc((size_t)B_*H2_*4);
  float* loss_b        = (float*)alloc((size_t)B_*4);

  hipLaunchKernelGGL(k_prep_enc, dim3(DG_), dim3(512), 0, stream,
                     Wihf, Wihb, bihf, bhhf, bihb, bhhb, Wenc, bsum);
  hipLaunchKernelGGL(k_prep_whh_bf, dim3(2*G_), dim3(E_), 0, stream, Whhf, Whhb, wtbf);
  hipLaunchKernelGGL(k_prep_dec, dim3(DG_), dim3(64), 0, stream, Wdec, dbih, dbhh, wdt, bsumd);
  hipLaunchKernelGGL(k_xstat, dim3(B_), dim3(H2_), 0, stream, X, SX, SX2);
  hipLaunchKernelGGL(k_gemm_pre, dim3(16, 512), dim3(256), 0, stream, X, Wenc, bsum, pre);
  hipLaunchKernelGGL(k_enc_mfma, dim3(16), dim3(512), 0, stream, pre, wtbf, SH, x0);
  hipLaunchKernelGGL(k_dec, dim3(B_), dim3(512), 0, stream, X, wdt, bsumd, x0, SX, SX2, loss_b);
  hipLaunchKernelGGL(k_out, dim3(B_), dim3(256), 0, stream, SX, SH, outW, outWb, loss_b, out);
}

// Round 9
// 4384.028 us; speedup vs baseline: 6.2433x; 2.2206x over previous
//
#include <hip/hip_runtime.h>
#include <hip/hip_bf16.h>
#include <hip/hip_fp16.h>
#include <stdint.h>

#define B_ 128
#define S_ 512
#define E_ 256
#define H2_ 512
#define G_ 1024      // 4*E
#define DG_ 2048     // 4*H2
#define M_ (B_*S_)   // 65536

typedef float f32x4 __attribute__((ext_vector_type(4)));
typedef short s16x8 __attribute__((ext_vector_type(8)));
typedef _Float16 h16x2 __attribute__((ext_vector_type(2)));

__device__ __forceinline__ float sigm(float x){ return 1.f/(1.f+__expf(-x)); }
__device__ __forceinline__ float tanh_f(float x){ return 1.f - 2.f/(__expf(2.f*x)+1.f); }

// ---------------- fp8 e4m3fn encode (prep-time) ----------------
__device__ __forceinline__ uint32_t enc_e4m3(float f){
  uint32_t u = __float_as_uint(f);
  uint32_t s = (u >> 24) & 0x80u;
  float af = fabsf(f);
  if (!(af > 0.f)) return s;
  if (af >= 448.f) return s | 0x7Eu;
  int ex = (int)((u >> 23) & 0xFF) - 127;
  uint32_t man = u & 0x7FFFFFu;
  int bexp = ex + 7;
  if (bexp <= 0){
    uint32_t qi = (uint32_t)rintf(af * 512.f);
    if (qi > 8u) qi = 8u;
    return s | qi;
  }
  uint32_t keep = man >> 20;
  uint32_t rest = man & 0xFFFFFu;
  const uint32_t half = 0x80000u;
  if (rest > half || (rest == half && (keep & 1u))) keep++;
  if (keep == 8u){ keep = 0u; bexp++; }
  if (bexp >= 16) return s | 0x7Eu;
  if (bexp == 15 && keep == 7u) keep = 6u; // avoid NaN encoding
  return s | ((uint32_t)bexp << 3) | keep;
}

__device__ __forceinline__ uint32_t f32_to_fp8_byte(float v){
#if __has_builtin(__builtin_amdgcn_cvt_pk_fp8_f32)
  int pk = __builtin_amdgcn_cvt_pk_fp8_f32(v, v, 0, false);
  return (uint32_t)pk & 0xFFu;
#else
  return enc_e4m3(v);
#endif
}

__device__ __forceinline__ float dot2_f16(uint32_t a, uint32_t b, float acc){
#if __has_builtin(__builtin_amdgcn_fdot2)
  return __builtin_amdgcn_fdot2(__builtin_bit_cast(h16x2,a), __builtin_bit_cast(h16x2,b), acc, false);
#else
  __half2 ah = __builtin_bit_cast(__half2, a), bh = __builtin_bit_cast(__half2, b);
  float2 af = __half22float2(ah), bf = __half22float2(bh);
  return fmaf(af.x, bf.x, fmaf(af.y, bf.y, acc));
#endif
}

// ---------------- weight prep ----------------
__global__ __launch_bounds__(512) void k_prep_enc(
    const float* __restrict__ wf, const float* __restrict__ wb,
    const float* __restrict__ bihf, const float* __restrict__ bhhf,
    const float* __restrict__ bihb, const float* __restrict__ bhhb,
    ushort* __restrict__ Wenc, float* __restrict__ bsum){
  int n = blockIdx.x, d = threadIdx.x;
  const float* src = (n < G_) ? (wf + (size_t)n*H2_) : (wb + (size_t)(n-G_)*H2_);
  __hip_bfloat16 h = __float2bfloat16(src[d]);
  Wenc[(size_t)n*H2_ + d] = __builtin_bit_cast(ushort, h);
  if (d == 0) bsum[n] = (n < G_) ? (bihf[n] + bhhf[n]) : (bihb[n-G_] + bhhb[n-G_]);
}

// Whh fp8, frag-major packed for the per-step MFMA stream:
// block bid = ((dir*8 + wid)*8 + tl)*4 + p ; lane holds 16 B = kk-pair (2p,2p+1)
// fragment bytes for row = wid*128 + tl*16 + (lane&15), k = kk*32 + (lane>>4)*8 + e
__global__ __launch_bounds__(64) void k_prep_whh_pk(
    const float* __restrict__ whf, const float* __restrict__ whb, uint8_t* __restrict__ Wp){
  int bid = blockIdx.x;            // 0..511
  int lane = threadIdx.x;          // 0..63
  int d   = bid >> 8;
  int rem = bid & 255;
  int wid = rem >> 5;
  int tl  = (rem >> 2) & 7;
  int p   = rem & 3;
  const float* src = d ? whb : whf;
  int row = wid*128 + tl*16 + (lane & 15);
  int hk  = (lane >> 4) * 8;
  uint8_t bytes[16];
  #pragma unroll
  for (int e = 0; e < 8; ++e){
    bytes[e]     = (uint8_t)enc_e4m3(src[(size_t)row*E_ + (2*p)*32   + hk + e]);
    bytes[8 + e] = (uint8_t)enc_e4m3(src[(size_t)row*E_ + (2*p+1)*32 + hk + e]);
  }
  uint8_t* dst = Wp + ((size_t)bid)*1024 + lane*16;
  *(uint4*)dst = *(const uint4*)bytes;
}

__global__ __launch_bounds__(64) void k_prep_dec(
    const float* __restrict__ wd, const float* __restrict__ bih, const float* __restrict__ bhh,
    uint4* __restrict__ wdt, float* __restrict__ bsumd){
  int row = blockIdx.x, u = threadIdx.x; // u in [0,64)
  const float* src = wd + (size_t)row*H2_ + u*8;
  union { _Float16 h[8]; uint4 q; } pk;
  #pragma unroll
  for (int i=0;i<8;i++) pk.h[i] = (_Float16)src[i];
  wdt[(size_t)u*DG_ + row] = pk.q;
  if (u == 0) bsumd[row] = bih[row] + bhh[row];
}

// ---------------- input stats ----------------
__global__ __launch_bounds__(512) void k_xstat(
    const float* __restrict__ X, float* __restrict__ SX, float* __restrict__ SX2){
  int b = blockIdx.x, d = threadIdx.x;
  const float* xb = X + (size_t)b*S_*H2_;
  float s=0.f, s2=0.f;
  for (int t=0;t<S_;++t){ float v = xb[(size_t)t*H2_ + d]; s += v; s2 = fmaf(v,v,s2); }
  SX[(size_t)b*H2_+d]=s; SX2[(size_t)b*H2_+d]=s2;
}

// ---------------- pre-GEMM: pre[m][n] = X[m][:] . Wenc[n][:] + bsum[n] ----------------
__global__ __launch_bounds__(256) void k_gemm_pre(
    const float* __restrict__ X, const ushort* __restrict__ Wenc,
    const float* __restrict__ bsum, __hip_bfloat16* __restrict__ pre){
  __shared__ ushort As[128][64];
  __shared__ ushort Bs[128][64];
  int n0 = blockIdx.x * 128, m0 = blockIdx.y * 128;
  int tid = threadIdx.x, lane = tid & 63, wid = tid >> 6;
  int wr = wid >> 1, wc = wid & 1;
  f32x4 acc[4][4] = {};
  for (int kt=0; kt<8; ++kt){
    int k0 = kt*64;
    #pragma unroll
    for (int it=0; it<4; ++it){
      int slot = tid + it*256;
      int r = slot >> 3, c8 = (slot & 7)*8;
      const float* ap = X + (size_t)(m0+r)*512 + k0 + c8;
      float4 a0 = *(const float4*)ap;
      float4 a1 = *(const float4*)(ap+4);
      union { __hip_bfloat16 h[8]; uint4 q; } pk;
      pk.h[0]=__float2bfloat16(a0.x); pk.h[1]=__float2bfloat16(a0.y);
      pk.h[2]=__float2bfloat16(a0.z); pk.h[3]=__float2bfloat16(a0.w);
      pk.h[4]=__float2bfloat16(a1.x); pk.h[5]=__float2bfloat16(a1.y);
      pk.h[6]=__float2bfloat16(a1.z); pk.h[7]=__float2bfloat16(a1.w);
      *(uint4*)&As[r][c8] = pk.q;
      *(uint4*)&Bs[r][c8] = *(const uint4*)(Wenc + (size_t)(n0+r)*512 + k0 + c8);
    }
    __syncthreads();
    #pragma unroll
    for (int kk=0; kk<2; ++kk){
      int krow = kk*32 + (lane>>4)*8;
      s16x8 af[4], bf[4];
      #pragma unroll
      for (int mi=0;mi<4;mi++) af[mi] = *(const s16x8*)&As[wr*64+mi*16+(lane&15)][krow];
      #pragma unroll
      for (int ni=0;ni<4;ni++) bf[ni] = *(const s16x8*)&Bs[wc*64+ni*16+(lane&15)][krow];
      #pragma unroll
      for (int mi=0;mi<4;mi++){
        #pragma unroll
        for (int ni=0;ni<4;ni++)
          acc[mi][ni] = __builtin_amdgcn_mfma_f32_16x16x32_bf16(af[mi], bf[ni], acc[mi][ni], 0,0,0);
      }
    }
    __syncthreads();
  }
  #pragma unroll
  for (int ni=0; ni<4; ++ni){
    int n = n0 + wc*64 + ni*16 + (lane&15);
    float bs = bsum[n];
    #pragma unroll
    for (int mi=0; mi<4; ++mi){
      int mb = m0 + wr*64 + mi*16 + (lane>>4)*4;
      #pragma unroll
      for (int r2=0;r2<4;r2++)
        pre[(size_t)(mb+r2)*DG_ + n] = __float2bfloat16(acc[mi][ni][r2] + bs);
    }
  }
}

// ---------------- encoder recurrence v9: fp8 MFMA GEMM per step ----------------
// v8 skeleton (validated) with: W fp8 frag-major packed (coalesced b128 stream,
// 256 KB/step), h fp8 in LDS (A-operand), pre-loads issued at loop top.
__global__ __launch_bounds__(512) void k_enc_mfma(
    const __hip_bfloat16* __restrict__ pre, const uint8_t* __restrict__ Wp,
    float* __restrict__ SH, float* __restrict__ x0){
  int wg = blockIdx.x;            // 0..15
  int dir = wg >> 3;
  int b0 = (wg & 7) * 16;
  int t = threadIdx.x, lane = t & 63, wid = t >> 6;
  __shared__ __align__(16) float   gbuf[1024*17];   // 68 KB
  __shared__ __align__(16) uint8_t hbf8[16*264];    // 4.1 KB fp8 h (264 = row pad)
  __shared__ __align__(16) ushort  pbuf[16*1024];   // 32 KB

  for (int i = t; i < 16*264; i += 512) hbf8[i] = 0;

  int mc = t >> 5, ub = t & 31;        // combine role
  float c_st[8] = {0,0,0,0,0,0,0,0};
  float sumh[8] = {0,0,0,0,0,0,0,0};

  // wave's packed-W stream base: 32 KB contiguous per wave
  const uint4* wp0 = (const uint4*)(Wp + ((size_t)(dir*8 + wid))*32*1024);
  int frow = lane & 15;
  int fk8  = (lane >> 4) * 8;          // byte offset within 32-k window
  int sm = t >> 5;                     // staging: chain m
  int sc = (t & 31) * 32;              // staging: col offset (bf16 units)
  __syncthreads();

  for (int s = 0; s < S_; ++s){
    // ---- A-frags from LDS (fp8 h) ----
    long long a_ll[8];
    {
      const uint8_t* ar = &hbf8[frow*264 + fk8];
      #pragma unroll
      for (int kk=0; kk<8; ++kk){
        uint2 v = *(const uint2*)(ar + kk*32);
        a_ll[kk] = (((long long)v.y) << 32) | (unsigned int)v.x;
      }
    }
    // ---- issue pre-tile loads early (HBM latency hides under MFMA phase) ----
    int ts = dir ? (S_-1 - s) : s;
    const uint4* psrc = (const uint4*)(pre + ((size_t)((b0+sm)*S_ + ts))*DG_ + dir*G_ + sc);
    uint4 pv0 = psrc[0], pv1 = psrc[1], pv2 = psrc[2], pv3 = psrc[3];
    // ---- P1: MFMA, B streamed coalesced from L2-resident packed fp8 W ----
    const uint4* wl = wp0;
    asm volatile("" : "+v"(wl));       // anti-LICM: re-issue W loads each step
    f32x4 acc[8] = {};
    #pragma unroll
    for (int tl=0; tl<8; ++tl){
      #pragma unroll
      for (int p=0; p<4; ++p){
        uint4 q = wl[(tl*4 + p)*64 + lane];
        long long b0f = (((long long)q.y) << 32) | (unsigned int)q.x;
        long long b1f = (((long long)q.w) << 32) | (unsigned int)q.z;
        acc[tl] = __builtin_amdgcn_mfma_f32_16x16x32_fp8_fp8(a_ll[2*p],   b0f, acc[tl], 0,0,0);
        acc[tl] = __builtin_amdgcn_mfma_f32_16x16x32_fp8_fp8(a_ll[2*p+1], b1f, acc[tl], 0,0,0);
      }
    }
    // ---- P2: C -> gbuf (stride 17), pre -> pbuf ----
    #pragma unroll
    for (int tl=0; tl<8; ++tl){
      int n = wid*128 + tl*16 + frow;
      int mb = (lane>>4)*4;
      gbuf[n*17 + mb + 0] = acc[tl][0];
      gbuf[n*17 + mb + 1] = acc[tl][1];
      gbuf[n*17 + mb + 2] = acc[tl][2];
      gbuf[n*17 + mb + 3] = acc[tl][3];
    }
    { uint4* pd = (uint4*)&pbuf[sm*1024 + sc];
      pd[0]=pv0; pd[1]=pv1; pd[2]=pv2; pd[3]=pv3; }
    __syncthreads();
    // ---- P3: gates + state update ----
    int wx0 = (dir==0 && s==S_-1) || (dir==1 && s==0);
    #pragma unroll
    for (int r=0; r<8; ++r){
      int u = ub + r*32;
      float gi = gbuf[u*17 + mc];
      float gf = gbuf[(u+256)*17 + mc];
      float gg = gbuf[(u+512)*17 + mc];
      float go = gbuf[(u+768)*17 + mc];
      gi += __bfloat162float(__builtin_bit_cast(__hip_bfloat16, pbuf[mc*1024 + u]));
      gf += __bfloat162float(__builtin_bit_cast(__hip_bfloat16, pbuf[mc*1024 + u + 256]));
      gg += __bfloat162float(__builtin_bit_cast(__hip_bfloat16, pbuf[mc*1024 + u + 512]));
      go += __bfloat162float(__builtin_bit_cast(__hip_bfloat16, pbuf[mc*1024 + u + 768]));
      float cn = sigm(gf)*c_st[r] + sigm(gi)*tanh_f(gg);
      float hn = sigm(go)*tanh_f(cn);
      c_st[r] = cn;
      sumh[r] += hn;
      hbf8[mc*264 + u] = (uint8_t)f32_to_fp8_byte(hn);
      if (wx0) x0[(size_t)(b0+mc)*H2_ + dir*E_ + u] = hn;
    }
    __syncthreads();
  }
  #pragma unroll
  for (int r=0; r<8; ++r){
    int u = ub + r*32;
    SH[((size_t)dir*B_ + (b0+mc))*E_ + u] = sumh[r];
  }
}

// ---------------- decoder + ae_loss: 128 wgs = b, 512 thr = hidden dim ----------------
#define EPS_CONV 2e-6f
__global__ __launch_bounds__(512) void k_dec(
    const float* __restrict__ X, const uint4* __restrict__ wdt,
    const float* __restrict__ bsumd, const float* __restrict__ x0,
    const float* __restrict__ SX, const float* __restrict__ SX2,
    float* __restrict__ loss_b){
  int b = blockIdx.x, j = threadIdx.x;
  __shared__ _Float16 hl[512];
  __shared__ float red[512];
  float h = x0[(size_t)b*H2_ + j];
  hl[j] = (_Float16)h;
  float bi = bsumd[j], bg = bsumd[j+1024], bo = bsumd[j+1536];
  float sxp = 0.f, x2p = 0.f, lacc = 0.f;
  const float* xb = X + (size_t)b*S_*H2_;
  int done = S_;
  __syncthreads();
  for (int s=0; s<S_; ++s){
    float ai = bi, ag = bg, ao = bo;
    const uint4* hp = (const uint4*)hl;
    const uint4* wi = wdt + j;
    const uint4* wgp = wdt + j + 1024;
    const uint4* wo = wdt + j + 1536;
    #pragma unroll 8
    for (int u=0; u<64; ++u){
      uint4 hv = hp[u];
      uint4 a = wi[(size_t)u*DG_];
      uint4 g = wgp[(size_t)u*DG_];
      uint4 o = wo[(size_t)u*DG_];
      ai = dot2_f16(a.x, hv.x, ai); ai = dot2_f16(a.y, hv.y, ai);
      ai = dot2_f16(a.z, hv.z, ai); ai = dot2_f16(a.w, hv.w, ai);
      ag = dot2_f16(g.x, hv.x, ag); ag = dot2_f16(g.y, hv.y, ag);
      ag = dot2_f16(g.z, hv.z, ag); ag = dot2_f16(g.w, hv.w, ag);
      ao = dot2_f16(o.x, hv.x, ao); ao = dot2_f16(o.y, hv.y, ao);
      ao = dot2_f16(o.z, hv.z, ao); ao = dot2_f16(o.w, hv.w, ao);
    }
    float cc = sigm(ai) * tanh_f(ag);
    float hn = sigm(ao) * tanh_f(cc);
    float xv = xb[(size_t)s*H2_ + j];
    float dd = xv - hn;
    lacc += dd*dd; sxp += xv; x2p = fmaf(xv,xv,x2p);
    float delta = fabsf(hn - h);
    h = hn;
    __syncthreads();                      // all dot-reads of old hl done
    hl[j] = (_Float16)h;
    // race-free convergence vote: single counting barrier, uniform result
    if (__syncthreads_count(delta > EPS_CONV) == 0){ done = s+1; break; }
  }
  if (done < S_){
    size_t o = (size_t)b*H2_ + j;
    float rx = SX[o] - sxp, rx2 = SX2[o] - x2p;
    float rem = (float)(S_ - done);
    lacc += rx2 - 2.f*h*rx + rem*h*h;
  }
  red[j] = lacc;
  __syncthreads();
  for (int st=256; st>0; st>>=1){
    if (j < st) red[j] += red[j+st];
    __syncthreads();
  }
  if (j == 0) loss_b[b] = red[0];
}

// ---------------- output head ----------------
__global__ __launch_bounds__(256) void k_out(
    const float* __restrict__ SX, const float* __restrict__ SH,
    const float* __restrict__ outW, const float* __restrict__ outWb,
    const float* __restrict__ loss_b, float* __restrict__ out){
  int b = blockIdx.x, o = threadIdx.x;
  __shared__ float pooled[512];
  for (int d=o; d<512; d+=256){
    float v = SX[(size_t)b*H2_ + d];
    v += (d < E_) ? SH[(size_t)b*E_ + d] : SH[(size_t)(B_ + b)*E_ + (d - E_)];
    pooled[d] = v;
  }
  __syncthreads();
  const float4* w4 = (const float4*)(outW + (size_t)o*H2_);
  const float4* p4 = (const float4*)pooled;
  float acc = outWb[o];
  #pragma unroll 16
  for (int i=0;i<128;i++){
    float4 w = w4[i], p = p4[i];
    acc = fmaf(w.x,p.x,acc); acc = fmaf(w.y,p.y,acc);
    acc = fmaf(w.z,p.z,acc); acc = fmaf(w.w,p.w,acc);
  }
  out[(size_t)b*256 + o] = acc;
  if (b == 0 && o == 0){
    float L = 0.f;
    for (int i=0;i<B_;i++) L += loss_b[i];
    out[32768] = L / 33554432.f;
  }
}

extern "C" void kernel_launch(void* const* d_in, const int* in_sizes, int n_in,
                              void* d_out, int out_size, void* d_ws, size_t ws_size,
                              hipStream_t stream) {
  const float* X     = (const float*)d_in[0];
  const float* Wihf  = (const float*)d_in[1];
  const float* Whhf  = (const float*)d_in[2];
  const float* bihf  = (const float*)d_in[3];
  const float* bhhf  = (const float*)d_in[4];
  const float* Wihb  = (const float*)d_in[5];
  const float* Whhb  = (const float*)d_in[6];
  const float* bihb  = (const float*)d_in[7];
  const float* bhhb  = (const float*)d_in[8];
  const float* Wdec  = (const float*)d_in[9];
  const float* dbih  = (const float*)d_in[10];
  const float* dbhh  = (const float*)d_in[11];
  // d_in[12..15]: attW/attW_b/attU/attU_b are mathematically dead (softmax over size-1 axis)
  const float* outW  = (const float*)d_in[16];
  const float* outWb = (const float*)d_in[17];
  float* out = (float*)d_out;

  char* ws = (char*)d_ws;
  size_t off = 0;
  auto alloc = [&](size_t bytes){ void* p = ws + off; off += (bytes + 255) & ~(size_t)255; return p; };
  __hip_bfloat16* pre  = (__hip_bfloat16*)alloc((size_t)M_*DG_*2);   // 268 MB
  ushort* Wenc         = (ushort*)alloc((size_t)DG_*H2_*2);
  float* bsum          = (float*)alloc((size_t)DG_*4);
  uint8_t* Wp          = (uint8_t*)alloc((size_t)2*G_*E_);           // 512 KB packed fp8 Whh
  uint4* wdt           = (uint4*)alloc((size_t)64*DG_*16);
  float* bsumd         = (float*)alloc((size_t)DG_*4);
  float* SX            = (float*)alloc((size_t)B_*H2_*4);
  float* SX2           = (float*)alloc((size_t)B_*H2_*4);
  float* SH            = (float*)alloc((size_t)2*B_*E_*4);
  float* x0            = (float*)alloc((size_t)B_*H2_*4);
  float* loss_b        = (float*)alloc((size_t)B_*4);

  hipLaunchKernelGGL(k_prep_enc, dim3(DG_), dim3(512), 0, stream,
                     Wihf, Wihb, bihf, bhhf, bihb, bhhb, Wenc, bsum);
  hipLaunchKernelGGL(k_prep_whh_pk, dim3(512), dim3(64), 0, stream, Whhf, Whhb, Wp);
  hipLaunchKernelGGL(k_prep_dec, dim3(DG_), dim3(64), 0, stream, Wdec, dbih, dbhh, wdt, bsumd);
  hipLaunchKernelGGL(k_xstat, dim3(B_), dim3(H2_), 0, stream, X, SX, SX2);
  hipLaunchKernelGGL(k_gemm_pre, dim3(16, 512), dim3(256), 0, stream, X, Wenc, bsum, pre);
  hipLaunchKernelGGL(k_enc_mfma, dim3(16), dim3(512), 0, stream, pre, Wp, SH, x0);
  hipLaunchKernelGGL(k_dec, dim3(B_), dim3(512), 0, stream, X, wdt, bsumd, x0, SX, SX2, loss_b);
  hipLaunchKernelGGL(k_out, dim3(B_), dim3(256), 0, stream, SX, SH, outW, outWb, loss_b, out);
}